// Round 1
// baseline (766.167 us; speedup 1.0000x reference)
//
#include <hip/hip_runtime.h>
#include <hip/hip_bf16.h>

// Problem constants (fixed by the reference file).
#define K_OFF 27
#define M_PTS 100000
#define C_CH 64
#define N_OUT_PTS 400000
#define BN_EPS 1e-5f

#define TILE_PTS 16
#define NT (M_PTS / TILE_PTS)   // 6250 16-point tiles per k-offset (exact)
#define BLKX 32                 // blocks.x per k  -> 128 waves per k
#define WSTRIDE (BLKX * 4)

typedef __attribute__((ext_vector_type(8))) short short8;  // 8 bf16 = 4 VGPRs
typedef __attribute__((ext_vector_type(4))) float f32x4;

// Packed 2xbf16 atomic add. gfx950 HAS global_atomic_pk_add_bf16 (CDNA3+).
__device__ inline void pk_atomic_add_bf16(__hip_bfloat16* p, int bits) {
#if __has_builtin(__builtin_amdgcn_global_atomic_fadd_v2bf16)
    typedef short s2v __attribute__((ext_vector_type(2)));
    typedef __attribute__((address_space(1))) s2v* gp;
    s2v v;
    __builtin_memcpy(&v, &bits, 4);
    __builtin_amdgcn_global_atomic_fadd_v2bf16((gp)(unsigned long long)p, v);
#else
    asm volatile("global_atomic_pk_add_bf16 %0, %1, off"
                 :: "v"((unsigned long long)p), "v"(bits) : "memory");
#endif
}

__device__ inline short bf16c(float f) {
    return __builtin_bit_cast(short, __float2bfloat16(f));
}

// cvt staged fp32 rows -> A frags, 8x MFMA, pack + pk-bf16 atomic scatter.
// Lane l (g=l>>4, c=l&15): A row = point c of the tile, k-slice 8g..8g+7
// (per K-step). D layout (m89-verified): col=c (N-tile tt -> cout 4c+tt),
// row = 4g + reg. So lane l's acc[0..3][e] are couts 4c..4c+3 of point 4g+e:
// two adjacent-channel pk atomics, NO cross-lane shuffles.
__device__ __attribute__((always_inline)) inline void tile_compute(
    const float4* cur, const int* dstv, const short8 bfrag[2][4],
    __hip_bfloat16* __restrict__ out_ws, int c)
{
    short8 af0, af1;
    #pragma unroll
    for (int j = 0; j < 4; ++j) {
        af0[j]     = bf16c(cur[0][j]);
        af0[j + 4] = bf16c(cur[1][j]);
        af1[j]     = bf16c(cur[2][j]);
        af1[j + 4] = bf16c(cur[3][j]);
    }
    f32x4 acc[4];
    #pragma unroll
    for (int tt = 0; tt < 4; ++tt) {
        f32x4 z = {0.f, 0.f, 0.f, 0.f};
        z       = __builtin_amdgcn_mfma_f32_16x16x32_bf16(af0, bfrag[0][tt], z, 0, 0, 0);
        acc[tt] = __builtin_amdgcn_mfma_f32_16x16x32_bf16(af1, bfrag[1][tt], z, 0, 0, 0);
    }
    #pragma unroll
    for (int e = 0; e < 4; ++e) {
        __hip_bfloat16* rp = out_ws + (size_t)dstv[e] * C_CH + 4 * c;
        union { __hip_bfloat162 h; int i; } p0, p1;
        p0.h = __hip_bfloat162(__float2bfloat16(acc[0][e]), __float2bfloat16(acc[1][e]));
        p1.h = __hip_bfloat162(__float2bfloat16(acc[2][e]), __float2bfloat16(acc[3][e]));
        pk_atomic_add_bf16(rp, p0.i);
        pk_atomic_add_bf16(rp + 2, p1.i);
    }
}

// ---------------------------------------------------------------------------
// Kernel 1: gather -> MFMA 16x16x32 bf16 GEMM -> pk-bf16 atomic scatter.
// One wave owns 16-point tiles (grid-stride). W[k] cached in regs as 8 bf16
// B-fragments, column-permuted (N-tile tt covers couts {4c+tt}) so the
// epilogue needs zero shuffles. Pipeline: idx 2 tiles ahead, gather 1 ahead.
// ---------------------------------------------------------------------------
__global__ __launch_bounds__(256, 4) void scatter_gemm(
    const float* __restrict__ x, const float* __restrict__ W,
    const int* __restrict__ in_idx, const int* __restrict__ out_idx,
    __hip_bfloat16* __restrict__ out_ws)
{
    const int k = blockIdx.y;
    const int lane = threadIdx.x & 63;
    const int wave = threadIdx.x >> 6;
    const int g = lane >> 4;
    const int c = lane & 15;

    // B fragments: bfrag[s][tt], element j = W[k][cin = 32s+8g+j][cout = 4c+tt].
    const float* __restrict__ Wk = W + (size_t)k * C_CH * C_CH;
    short8 bfrag[2][4];
    #pragma unroll
    for (int s = 0; s < 2; ++s) {
        #pragma unroll
        for (int tt = 0; tt < 4; ++tt) {
            short8 v;
            #pragma unroll
            for (int j = 0; j < 8; ++j)
                v[j] = bf16c(Wk[(size_t)(32 * s + 8 * g + j) * C_CH + 4 * c + tt]);
            bfrag[s][tt] = v;
        }
    }

    const int kbase = k * M_PTS;
    const int t0 = blockIdx.x * 4 + wave;   // 0..127 < NT always

    // ---- prologue: stage tile t0 fully, idx for t0+WSTRIDE
    int src_c = in_idx[kbase + t0 * TILE_PTS + c];
    int dstv[4];
    #pragma unroll
    for (int e = 0; e < 4; ++e)
        dstv[e] = out_idx[kbase + t0 * TILE_PTS + 4 * g + e];
    float4 cur[4];
    {
        const float4* xr = (const float4*)x + (size_t)src_c * 16;
        cur[0] = xr[2 * g];     cur[1] = xr[2 * g + 1];      // cin 8g..8g+7
        cur[2] = xr[8 + 2 * g]; cur[3] = xr[8 + 2 * g + 1];  // cin 32+8g..
    }
    int src_n = (t0 + WSTRIDE < NT) ? in_idx[kbase + (t0 + WSTRIDE) * TILE_PTS + c] : 0;

    int t = t0;
    for (; t + WSTRIDE < NT; t += WSTRIDE) {
        const int tn = t + WSTRIDE;
        // prefetch tile tn (gather + dst ids) and idx for tn+WSTRIDE
        float4 nxt[4]; int dstn[4];
        {
            const float4* xr = (const float4*)x + (size_t)src_n * 16;
            nxt[0] = xr[2 * g];     nxt[1] = xr[2 * g + 1];
            nxt[2] = xr[8 + 2 * g]; nxt[3] = xr[8 + 2 * g + 1];
            #pragma unroll
            for (int e = 0; e < 4; ++e)
                dstn[e] = out_idx[kbase + tn * TILE_PTS + 4 * g + e];
        }
        const int t2 = tn + WSTRIDE;
        const int src_2 = (t2 < NT) ? in_idx[kbase + t2 * TILE_PTS + c] : 0;

        tile_compute(cur, dstv, bfrag, out_ws, c);

        #pragma unroll
        for (int j = 0; j < 4; ++j) cur[j] = nxt[j];
        #pragma unroll
        for (int e = 0; e < 4; ++e) dstv[e] = dstn[e];
        src_c = src_n;
        src_n = src_2;
    }
    // epilogue: last tile, no prefetch
    tile_compute(cur, dstv, bfrag, out_ws, c);
}

// ---------------------------------------------------------------------------
// Kernel 2: per-channel sum / sumsq over bf16 accumulator. (unchanged)
// ---------------------------------------------------------------------------
__global__ __launch_bounds__(256) void bn_stats(
    const __hip_bfloat16* __restrict__ ws, float* __restrict__ stats)
{
    const uint4* in = (const uint4*)ws;
    const size_t n = (size_t)N_OUT_PTS * C_CH / 8;   // 3.2M uint4s
    const size_t stride = (size_t)gridDim.x * blockDim.x;
    float s[8], s2[8];
    #pragma unroll
    for (int j = 0; j < 8; ++j) { s[j] = 0.f; s2[j] = 0.f; }
    for (size_t i = (size_t)blockIdx.x * blockDim.x + threadIdx.x; i < n; i += stride) {
        uint4 q = in[i];
        unsigned wds[4] = {q.x, q.y, q.z, q.w};
        #pragma unroll
        for (int j = 0; j < 4; ++j) {
            __hip_bfloat162 h = *(__hip_bfloat162*)&wds[j];
            float f0 = __low2float(h), f1 = __high2float(h);
            s[2 * j] += f0;  s2[2 * j] += f0 * f0;
            s[2 * j + 1] += f1; s2[2 * j + 1] += f1 * f1;
        }
    }
    __shared__ float sh[2][256][8];
    #pragma unroll
    for (int j = 0; j < 8; ++j) { sh[0][threadIdx.x][j] = s[j]; sh[1][threadIdx.x][j] = s2[j]; }
    __syncthreads();
    if (threadIdx.x < C_CH) {
        const int c = threadIdx.x;
        float ts = 0.f, t2 = 0.f;
        #pragma unroll
        for (int q = 0; q < 32; ++q) {
            ts += sh[0][8 * q + (c >> 3)][c & 7];
            t2 += sh[1][8 * q + (c >> 3)][c & 7];
        }
        unsafeAtomicAdd(&stats[c], ts);
        unsafeAtomicAdd(&stats[C_CH + c], t2);
    }
}

// ---------------------------------------------------------------------------
// Kernel 3: y = relu((ws - mean) * rsqrt(var+eps) * gamma + beta). (unchanged)
// ---------------------------------------------------------------------------
__global__ __launch_bounds__(256) void bn_apply(
    const __hip_bfloat16* __restrict__ ws, const float* __restrict__ stats,
    const float* __restrict__ gamma, const float* __restrict__ beta,
    float* __restrict__ out)
{
    const float inv_n = 1.0f / (float)N_OUT_PTS;
    const int c0 = 8 * (threadIdx.x & 7);
    float sc[8], bs[8];
    #pragma unroll
    for (int j = 0; j < 8; ++j) {
        int c = c0 + j;
        float mean = stats[c] * inv_n;
        float var = stats[C_CH + c] * inv_n - mean * mean;
        float s = gamma[c] * rsqrtf(var + BN_EPS);
        sc[j] = s;
        bs[j] = beta[c] - mean * s;
    }
    const uint4* in = (const uint4*)ws;
    float4* o4 = (float4*)out;
    const size_t n = (size_t)N_OUT_PTS * C_CH / 8;
    const size_t stride = (size_t)gridDim.x * blockDim.x;
    for (size_t i = (size_t)blockIdx.x * blockDim.x + threadIdx.x; i < n; i += stride) {
        uint4 q = in[i];
        unsigned wds[4] = {q.x, q.y, q.z, q.w};
        float f[8];
        #pragma unroll
        for (int j = 0; j < 4; ++j) {
            __hip_bfloat162 h = *(__hip_bfloat162*)&wds[j];
            f[2 * j] = __low2float(h);
            f[2 * j + 1] = __high2float(h);
        }
        float4 r0, r1;
        r0.x = fmaxf(fmaf(f[0], sc[0], bs[0]), 0.f);
        r0.y = fmaxf(fmaf(f[1], sc[1], bs[1]), 0.f);
        r0.z = fmaxf(fmaf(f[2], sc[2], bs[2]), 0.f);
        r0.w = fmaxf(fmaf(f[3], sc[3], bs[3]), 0.f);
        r1.x = fmaxf(fmaf(f[4], sc[4], bs[4]), 0.f);
        r1.y = fmaxf(fmaf(f[5], sc[5], bs[5]), 0.f);
        r1.z = fmaxf(fmaf(f[6], sc[6], bs[6]), 0.f);
        r1.w = fmaxf(fmaf(f[7], sc[7], bs[7]), 0.f);
        o4[2 * i] = r0;
        o4[2 * i + 1] = r1;
    }
}

extern "C" void kernel_launch(void* const* d_in, const int* in_sizes, int n_in,
                              void* d_out, int out_size, void* d_ws, size_t ws_size,
                              hipStream_t stream) {
    const float* x      = (const float*)d_in[0];
    const float* W      = (const float*)d_in[1];
    const float* gamma  = (const float*)d_in[2];
    const float* beta   = (const float*)d_in[3];
    const int*   in_idx = (const int*)d_in[4];
    const int*   out_idx= (const int*)d_in[5];
    float* out = (float*)d_out;

    __hip_bfloat16* out_ws = (__hip_bfloat16*)d_ws;       // N_OUT*64 bf16 accumulator
    const size_t acc_elems = (size_t)N_OUT_PTS * C_CH;
    float* stats = (float*)((char*)d_ws + acc_elems * sizeof(__hip_bfloat16));

    const size_t clear_bytes = acc_elems * sizeof(__hip_bfloat16) + 2 * C_CH * sizeof(float);
    (void)hipMemsetAsync(d_ws, 0, clear_bytes, stream);

    dim3 g1(BLKX, K_OFF);   // (32, 27) = 864 blocks, all co-resident at 4/CU
    scatter_gemm<<<g1, 256, 0, stream>>>(x, W, in_idx, out_idx, out_ws);

    bn_stats<<<2048, 256, 0, stream>>>(out_ws, stats);

    bn_apply<<<2048, 256, 0, stream>>>(out_ws, stats, gamma, beta, out);
}